// Round 20
// baseline (172.383 us; speedup 1.0000x reference)
//
#include <hip/hip_runtime.h>
#include <hip/hip_bf16.h>

// ---------------------------------------------------------------------------
// SimpleSelfAttention: out = softmax((xWq^T+bq)(xWk^T+bk)^T / 32) (xWv^T+bv)
// B=4, S=2048, E=1024, fp32 in/out. Internally bf16 MFMA, fp32 accum.
//
// R20 experiment: gemm33 = 128x128 tile, BK=32, THREE 16KB LDS buffers
// (48KB -> 3 blocks/CU) + counted vmcnt + ONE barrier/tile -- combines R6
// gemm8's pipeline (3-buf counted, proven race-free; tail fixed to drain)
// with R10 gemm97's occupancy (3 blocks/CU). Applied to VT + PV only;
// QK + scores stay on gemm256 (known 47.3us) => within-run A/B.
// LDS layout: R15's proven conflict-free packed-prow XOR ([64 prow][8 ch],
// logical (row,c): prow=row>>1, pch=((row&1)*4+c)^(prow&7)).
//
// gemm256 (8-phase, conflict-free, R15-17): QK + scores; softmax folded
// (scores epilogue exp + per-64col psum; reduce_rs; PV epilogue x 1/rs).
//
// ws: Q@0 | K@8M1 | P@16M1 ; rs over dead Q ; VT@8M1 over dead K
// d_out scratch: xb@0 | Wb@8M1 | psum@11M1 (all dead before PV writes)
// ---------------------------------------------------------------------------

typedef __attribute__((ext_vector_type(8))) short bf16x8;
typedef __attribute__((ext_vector_type(4))) float f32x4;

#define DEVI static __device__ __forceinline__

DEVI short to_bf16(float f) {
    unsigned u = __builtin_bit_cast(unsigned, f);
    u += 0x7fffu + ((u >> 16) & 1u);          // RNE (finite/normal inputs)
    return (short)(u >> 16);
}
DEVI float from_bf16(short s) {
    return __builtin_bit_cast(float, (unsigned)((unsigned short)s) << 16);
}

DEVI void gload_lds16(const short* g, short* l) {
    __builtin_amdgcn_global_load_lds(
        (const __attribute__((address_space(1))) void*)g,
        (__attribute__((address_space(3))) void*)l, 16, 0, 0);
}

#define BAR() __builtin_amdgcn_s_barrier()

// ============================ gemm256 (8-phase) ============================
// C[z][M][N] = scale*A[z].B[z]^T (+bias). bf16 K-major. K%64==0, K>=192.
// BIAS: 0=none, 1=col bias b_z[n]. EPI: 0=plain, 1=exp + psum partials.
template<int BIAS, int EPI, typename TOUT>
__global__ __launch_bounds__(512, 1)
void gemm256(const short* __restrict__ A, long lda, long bsA,
             const short* __restrict__ B, long ldb, long bsB,
             const float* __restrict__ b0, const float* __restrict__ b1,
             const float* __restrict__ b2,
             TOUT* __restrict__ c0, TOUT* __restrict__ c1, TOUT* __restrict__ c2,
             long ldc, long bsC, int K, float scale, float* __restrict__ ps)
{
    // half-tile = [128 prow][8 pchunk] 16B chunks (8192 shorts)
    __shared__ __align__(16) short Al[2][2][128 * 64];
    __shared__ __align__(16) short Bl[2][2][128 * 64];

    const int tid = threadIdx.x;
    const int z = blockIdx.z;
    const int gx = gridDim.x;
    const int nwg = gx * gridDim.y;
    const int id = blockIdx.y * gx + blockIdx.x;
    const int id2 = (id & 7) * (nwg >> 3) + (id >> 3);   // XCD swizzle (nwg%8==0)
    const long m0 = (long)(id2 / gx) * 256;
    const long n0 = (long)(id2 % gx) * 256;

    const short* Ab = A + (long)z * bsA + m0 * lda;
    const short* Bb = B + (long)z * bsB + n0 * ldb;

    const int wv = tid >> 6;
    const int wm = wv >> 2;            // 0..1 : M half
    const int wn = wv & 3;             // 0..3 : 64-col N strip
    const int lane = tid & 63;
    const int lrow = lane & 15;
    const int q = lane >> 4;           // k-quarter within a 32-k half

    const int NT = K >> 6;             // BK=64, NT>=3

    auto stA = [&](int t, int kh) {
        const long k0 = (long)t * 64 + kh * 32;
        short* dst = &Al[t & 1][kh][0];
        #pragma unroll
        for (int i = 0; i < 2; ++i) {
            int s = i * 512 + tid;
            int prow = s >> 3;
            int pch = (s & 7) ^ (prow & 7);
            int row = prow * 2 + (pch >> 2);
            gload_lds16(Ab + (long)row * lda + k0 + (pch & 3) * 8,
                        &dst[s * 8]);
        }
    };
    auto stB = [&](int t, int kh) {
        const long k0 = (long)t * 64 + kh * 32;
        short* dst = &Bl[t & 1][kh][0];
        #pragma unroll
        for (int i = 0; i < 2; ++i) {
            int s = i * 512 + tid;
            int prow = s >> 3;
            int pch = (s & 7) ^ (prow & 7);
            int row = prow * 2 + (pch >> 2);
            gload_lds16(Bb + (long)row * ldb + k0 + (pch & 3) * 8,
                        &dst[s * 8]);
        }
    };

    bf16x8 af[4], bf[4];
    auto rdA = [&](int b, int kh, int mh) {
        #pragma unroll
        for (int m = 0; m < 4; ++m) {
            int row = wm * 128 + (mh * 4 + m) * 16 + lrow;
            int prow = row >> 1;
            int pch = (((row & 1) * 4 + q)) ^ (prow & 7);
            af[m] = *(const bf16x8*)&Al[b][kh][prow * 64 + pch * 8];
        }
    };
    auto rdB = [&](int b, int kh) {
        #pragma unroll
        for (int n = 0; n < 4; ++n) {
            int row = wn * 64 + n * 16 + lrow;
            int prow = row >> 1;
            int pch = (((row & 1) * 4 + q)) ^ (prow & 7);
            bf[n] = *(const bf16x8*)&Bl[b][kh][prow * 64 + pch * 8];
        }
    };

    f32x4 acc[8][4] = {};

    // prologue: tile0 all 4 half-tiles + tile1 k0 half-tiles (12 loads)
    stA(0, 0); stB(0, 0); stA(0, 1); stB(0, 1);
    stA(1, 0); stB(1, 0);
    asm volatile("s_waitcnt vmcnt(4)" ::: "memory");   // tile0 landed
    __builtin_amdgcn_sched_barrier(0);
    BAR();

    for (int t = 0; t < NT; ++t) {
        const int b = t & 1;
        // ---- ph1: m0-3 x kk0 (reads Ak0, Bk0; stages (t+1).Ak1 -> buf^1)
        rdA(b, 0, 0); rdB(b, 0);
        if (t + 1 < NT) stA(t + 1, 1);
        BAR();
        __builtin_amdgcn_s_setprio(1);
        #pragma unroll
        for (int m = 0; m < 4; ++m)
            #pragma unroll
            for (int n = 0; n < 4; ++n)
                acc[m][n] = __builtin_amdgcn_mfma_f32_16x16x32_bf16(
                    af[m], bf[n], acc[m][n], 0, 0, 0);
        __builtin_amdgcn_s_setprio(0);
        BAR();
        // ---- ph2: m4-7 x kk0 (B held in regs; stages (t+1).Bk1)
        rdA(b, 0, 1);
        if (t + 1 < NT) stB(t + 1, 1);
        BAR();
        __builtin_amdgcn_s_setprio(1);
        #pragma unroll
        for (int m = 0; m < 4; ++m)
            #pragma unroll
            for (int n = 0; n < 4; ++n)
                acc[4 + m][n] = __builtin_amdgcn_mfma_f32_16x16x32_bf16(
                    af[m], bf[n], acc[4 + m][n], 0, 0, 0);
        __builtin_amdgcn_s_setprio(0);
        if (t < NT - 1) asm volatile("s_waitcnt vmcnt(8)" ::: "memory");
        else            asm volatile("s_waitcnt vmcnt(0)" ::: "memory");
        __builtin_amdgcn_sched_barrier(0);
        BAR();   // t.Ak1/Bk1 landed for all waves -> ph3 may read
        // ---- ph3: m0-3 x kk1 (stages (t+2).Ak0 over dead t.Ak0)
        rdA(b, 1, 0); rdB(b, 1);
        if (t + 2 < NT) stA(t + 2, 0);
        BAR();
        __builtin_amdgcn_s_setprio(1);
        #pragma unroll
        for (int m = 0; m < 4; ++m)
            #pragma unroll
            for (int n = 0; n < 4; ++n)
                acc[m][n] = __builtin_amdgcn_mfma_f32_16x16x32_bf16(
                    af[m], bf[n], acc[m][n], 0, 0, 0);
        __builtin_amdgcn_s_setprio(0);
        BAR();
        // ---- ph4: m4-7 x kk1 (stages (t+2).Bk0 over dead t.Bk0)
        rdA(b, 1, 1);
        if (t + 2 < NT) stB(t + 2, 0);
        BAR();
        __builtin_amdgcn_s_setprio(1);
        #pragma unroll
        for (int m = 0; m < 4; ++m)
            #pragma unroll
            for (int n = 0; n < 4; ++n)
                acc[4 + m][n] = __builtin_amdgcn_mfma_f32_16x16x32_bf16(
                    af[m], bf[n], acc[4 + m][n], 0, 0, 0);
        __builtin_amdgcn_s_setprio(0);
        if (t < NT - 2) asm volatile("s_waitcnt vmcnt(8)" ::: "memory");
        else            asm volatile("s_waitcnt vmcnt(0)" ::: "memory");
        __builtin_amdgcn_sched_barrier(0);
        BAR();   // (t+1).Ak0/Bk0 landed -> next tile ph1 may read
    }

    // epilogue: C/D layout col=lane&15, row=q*4+reg (verified m89)
    const float* bias = (z == 0) ? b0 : (z == 1) ? b1 : b2;
    TOUT* Cb = (((z == 0) ? c0 : (z == 1) ? c1 : c2) + (long)z * bsC)
               + m0 * ldc + n0;
    #pragma unroll
    for (int m = 0; m < 8; ++m) {
        #pragma unroll
        for (int r = 0; r < 4; ++r) {
            int row = wm * 128 + m * 16 + q * 4 + r;
            float rsum = 0.f;
            #pragma unroll
            for (int n = 0; n < 4; ++n) {
                int col = wn * 64 + n * 16 + lrow;
                float v = acc[m][n][r] * scale;
                if constexpr (BIAS == 1) v += bias[n0 + col];
                if constexpr (EPI == 1) { v = __expf(v); rsum += v; }
                if constexpr (sizeof(TOUT) == 2)
                    Cb[(long)row * ldc + col] = to_bf16(v);
                else
                    Cb[(long)row * ldc + col] = v;
            }
            if constexpr (EPI == 1) {
                rsum += __shfl_xor(rsum, 1);
                rsum += __shfl_xor(rsum, 2);
                rsum += __shfl_xor(rsum, 4);
                rsum += __shfl_xor(rsum, 8);
                if (lrow == 0) {
                    int j = (int)(n0 >> 6) + wn;     // 0..31
                    ps[((long)z * 32 + j) * 2048 + m0 + row] = rsum;
                }
            }
        }
    }
}

// ====== gemm33: 128x128, BK=32, 3-buffer counted pipeline, 3 blocks/CU =====
// BIAS: 0=none, 2=row bias b0[m]. EPI: 0=plain, 2=v *= 1/rs[row].
// Per tile: read 8 frags (buf b) | stage tile t+2 (buf (t+2)%3, dead) |
// 16 MFMA | [vmcnt(4) counted, tail drains] barrier. One barrier/tile.
template<int BIAS, int EPI, typename TOUT>
__global__ __launch_bounds__(256, 3)
void gemm33(const short* __restrict__ A, long lda, long bsA,
            const short* __restrict__ B, long ldb, long bsB,
            const float* __restrict__ b0,
            TOUT* __restrict__ C, long ldc, long bsC, int K, float scale,
            const float* __restrict__ rs, long rsLD)
{
    // tile = [64 prow][8 pchunk] 16B chunks (4096 shorts = 8KB each op)
    __shared__ __align__(16) short As[3][64 * 64];
    __shared__ __align__(16) short Bs[3][64 * 64];

    const int tid = threadIdx.x;
    const int z = blockIdx.z;

    const int gx = gridDim.x;
    const int nwg = gx * gridDim.y;
    const int id = blockIdx.y * gx + blockIdx.x;
    const int id2 = (id & 7) * (nwg >> 3) + (id >> 3);
    const long m0 = (long)(id2 / gx) * 128;
    const long n0 = (long)(id2 % gx) * 128;

    const short* Ab = A + (long)z * bsA + m0 * lda;
    const short* Bb = B + (long)z * bsB + n0 * ldb;

    const int wv = tid >> 6;
    const int lane = tid & 63;
    const int wr = (wv >> 1) * 64;
    const int wc = (wv & 1) * 64;
    const int lrow = lane & 15;
    const int q = lane >> 4;

    const int NT = K >> 5;             // BK=32, NT>=4

    // stage tile t (A+B 128x32) into buffer bb: 2+2 loads/thread.
    // chunk s: prow=s>>3, pch=(s&7)^(prow&7), row=2*prow+(pch>>2), c=pch&3.
    auto stage = [&](int t, int bb) {
        const long k0 = (long)t * 32;
        #pragma unroll
        for (int i = 0; i < 2; ++i) {
            int s = i * 256 + tid;            // 0..511
            int prow = s >> 3;
            int pch = (s & 7) ^ (prow & 7);
            int row = prow * 2 + (pch >> 2);
            gload_lds16(Ab + (long)row * lda + k0 + (pch & 3) * 8,
                        &As[bb][s * 8]);
        }
        #pragma unroll
        for (int i = 0; i < 2; ++i) {
            int s = i * 256 + tid;
            int prow = s >> 3;
            int pch = (s & 7) ^ (prow & 7);
            int row = prow * 2 + (pch >> 2);
            gload_lds16(Bb + (long)row * ldb + k0 + (pch & 3) * 8,
                        &Bs[bb][s * 8]);
        }
    };

    f32x4 acc[4][4] = {};

    stage(0, 0);
    stage(1, 1);
    asm volatile("s_waitcnt vmcnt(4)" ::: "memory");   // tile 0 landed
    __builtin_amdgcn_sched_barrier(0);
    BAR();

    int b = 0;
    for (int t = 0; t < NT; ++t) {
        bf16x8 af[4], bf[4];
        #pragma unroll
        for (int m = 0; m < 4; ++m) {
            int row = wr + m * 16 + lrow;
            int prow = row >> 1;
            int pch = (((row & 1) * 4 + q)) ^ (prow & 7);
            af[m] = *(const bf16x8*)&As[b][prow * 64 + pch * 8];
        }
        #pragma unroll
        for (int n = 0; n < 4; ++n) {
            int row = wc + n * 16 + lrow;
            int prow = row >> 1;
            int pch = (((row & 1) * 4 + q)) ^ (prow & 7);
            bf[n] = *(const bf16x8*)&Bs[b][prow * 64 + pch * 8];
        }

        const bool pre = (t + 2 < NT);
        if (pre) {
            int b2 = b + 2; if (b2 >= 3) b2 -= 3;
            stage(t + 2, b2);                // target buffer provably dead
        }

        __builtin_amdgcn_s_setprio(1);
        #pragma unroll
        for (int m = 0; m < 4; ++m)
            #pragma unroll
            for (int n = 0; n < 4; ++n)
                acc[m][n] = __builtin_amdgcn_mfma_f32_16x16x32_bf16(
                    af[m], bf[n], acc[m][n], 0, 0, 0);
        __builtin_amdgcn_s_setprio(0);

        if (t < NT - 1) {
            // t+1's loads landed: counted when t+2's 4 loads are in flight,
            // drain-0 in the tail (nothing younger in flight).
            if (pre) asm volatile("s_waitcnt vmcnt(4)" ::: "memory");
            else     asm volatile("s_waitcnt vmcnt(0)" ::: "memory");
            __builtin_amdgcn_sched_barrier(0);
            BAR();   // all waves' reads of buf b consumed; publish t+1
        }
        ++b; if (b == 3) b = 0;
    }

    TOUT* Cb = C + (long)z * bsC + m0 * ldc + n0;
    #pragma unroll
    for (int m = 0; m < 4; ++m) {
        #pragma unroll
        for (int r = 0; r < 4; ++r) {
            int row = wr + m * 16 + q * 4 + r;
            float iv = 1.0f;
            if constexpr (EPI == 2)
                iv = 1.0f / rs[(long)z * rsLD + m0 + row];
            #pragma unroll
            for (int n = 0; n < 4; ++n) {
                int col = wc + n * 16 + lrow;
                float v = acc[m][n][r] * scale;
                if constexpr (BIAS == 2) v += b0[m0 + row];
                if constexpr (EPI == 2) v *= iv;
                if constexpr (sizeof(TOUT) == 2)
                    Cb[(long)row * ldc + col] = to_bf16(v);
                else
                    Cb[(long)row * ldc + col] = v;
            }
        }
    }
}

// merged cvt: grid (512, 11). y<8: x chunks (fp32->bf16). y=8,9,10: Wq,Wk,Wv.
__global__ __launch_bounds__(256)
void cvt_all(const float* __restrict__ x,
             const float* __restrict__ wq, const float* __restrict__ wk,
             const float* __restrict__ wv, short* __restrict__ dst)
{
    const int y = blockIdx.y;
    const float* src;
    long dstOff8;
    long i;
    if (y < 8) {
        src = x;
        i = ((long)y * 512 + blockIdx.x) * 256 + threadIdx.x;
        dstOff8 = 0;
    } else {
        src = (y == 8) ? wq : (y == 9) ? wk : wv;
        i = (long)blockIdx.x * 256 + threadIdx.x;
        dstOff8 = (8l * 1024 * 1024 + (long)(y - 8) * 1024 * 1024) / 8;
    }
    float4 a = ((const float4*)src)[2 * i];
    float4 b = ((const float4*)src)[2 * i + 1];
    bf16x8 o = { to_bf16(a.x), to_bf16(a.y), to_bf16(a.z), to_bf16(a.w),
                 to_bf16(b.x), to_bf16(b.y), to_bf16(b.z), to_bf16(b.w) };
    *(bf16x8*)&dst[(dstOff8 + i) * 8] = o;
}

// rs[row] = sum_{j<32} ps[(z*32+j)*2048 + r]
__global__ __launch_bounds__(256)
void reduce_rs(const float* __restrict__ ps, float* __restrict__ rs)
{
    int row = blockIdx.x * 256 + threadIdx.x;   // 0..8191
    int z = row >> 11, r = row & 2047;
    const float* p = ps + (long)z * 32 * 2048 + r;
    float s = 0.f;
    #pragma unroll
    for (int j = 0; j < 32; ++j) s += p[j * 2048];
    rs[row] = s;
}

extern "C" void kernel_launch(void* const* d_in, const int* in_sizes, int n_in,
                              void* d_out, int out_size, void* d_ws, size_t ws_size,
                              hipStream_t stream)
{
    (void)in_sizes; (void)n_in; (void)out_size; (void)ws_size;

    const float* x  = (const float*)d_in[0];
    const float* Wq = (const float*)d_in[1];
    const float* bq = (const float*)d_in[2];
    const float* Wk = (const float*)d_in[3];
    const float* bk = (const float*)d_in[4];
    const float* Wv = (const float*)d_in[5];
    const float* bv = (const float*)d_in[6];
    float* out = (float*)d_out;

    const int S = 2048, E = 1024;
    const long M1 = 1024l * 1024;

    // ws regions (shorts)
    short* w  = (short*)d_ws;
    short* Q  = w;                  // [4][2048][1024]  (16MB)
    short* Kb = w + 8 * M1;         // [4][2048][1024]  (16MB)
    short* P  = w + 16 * M1;        // [4][2048][2048]  (32MB) exp(scores)
    float* rs = (float*)w;          // [4][2048] fp32 over dead Q
    short* VT = w + 8 * M1;         // [4][1024][2048] over dead K (post-scores)

    // d_out scratch (xb/Wb last read by VT-GEMM; psum by reduce_rs)
    short* dows = (short*)d_out;
    short* xb = dows;               // [8192][1024] bf16 (16MB)
    short* Wb = dows + 8 * M1;      // Wq,Wk,Wv bf16 (3 x 2MB)
    float* psum = (float*)(dows + 11 * M1);   // [4][32][2048] fp32 (1MB)

    dim3 blk(256), blk5(512);

    // 1. convert inputs to bf16
    cvt_all<<<dim3(512, 11), blk, 0, stream>>>(x, Wq, Wk, Wv, xb);

    // 2. Q,K projections (M=8192,N=1024,K=1024): 8-phase, grid 4x32x2 = 256
    gemm256<1, 0, short><<<dim3(4, 32, 2), blk5, 0, stream>>>(
        xb, E, 0, Wb, E, M1, bq, bk, nullptr, Q, Kb, nullptr, E, 0, E, 1.0f,
        nullptr);

    // 3. scores: P[z] = exp(Q K^T / 32) + psum (M=N=2048,K=1024): 8x8x4 = 256
    gemm256<0, 1, short><<<dim3(8, 8, 4), blk5, 0, stream>>>(
        Q, E, 2 * M1, Kb, E, 2 * M1, nullptr, nullptr, nullptr,
        P, P, P, S, 4 * M1, E, 0.03125f, psum);

    // 4. VT[z] = Wv xb[z]^T + bv (row bias) (M=1024,N=2048,K=1024): 16x8x4
    gemm33<2, 0, short><<<dim3(16, 8, 4), blk, 0, stream>>>(
        Wb + 2 * M1, E, 0, xb, E, 2 * M1, bv, VT, S, 2 * M1, E, 1.0f,
        nullptr, 0);

    // 5. rs[row] = sum of 32 partials (over dead Q)
    reduce_rs<<<dim3(32), blk, 0, stream>>>(psum, rs);

    // 6. out[z] = (P[z] VT[z]^T) / rs (M=2048,N=1024,K=2048): 8x16x4, fp32
    gemm33<0, 2, float><<<dim3(8, 16, 4), blk, 0, stream>>>(
        P, S, 4 * M1, VT, S, 2 * M1, nullptr, out, E, 2 * M1, S, 1.0f,
        rs, S);
}

// Round 22
// 164.353 us; speedup vs baseline: 1.0489x; 1.0489x over previous
//
#include <hip/hip_runtime.h>
#include <hip/hip_bf16.h>

// ---------------------------------------------------------------------------
// SimpleSelfAttention: out = softmax((xWq^T+bq)(xWk^T+bk)^T / 32) (xWv^T+bv)
// B=4, S=2048, E=1024, fp32 in/out. Internally bf16 MFMA, fp32 accum.
//
// == FINAL = R17/R19 configuration (validated twice: 164.0 / 164.3 us). ==
// R21's PV-rowsum fold raced (PV writes d_out over psum while other blocks
// still read it -> post-timing re-validation failed). reduce_rs must stay a
// separate dispatch ordered before PV.
//
// gemm256 (8-phase, QK + scores): 256x256 tile, BK=64, 8 waves (512 thr),
// per-wave out 128x64. LDS 128KB: [op][buf(2)][kh(2)] half-tiles in
// conflict-free XOR geometry ([128 prow][8 chunk], 128B rows; bank
// conflicts = 0). Counted vmcnt(8), never 0 mid-loop; stage targets
// provably dead; compiler's own lgkm waits order ds_read->MFMA.
//
// gemm97 (2-barrier 128x128, 3 blocks/CU, 80 VGPR no-spill): VT + PV.
// Softmax folded: scores epilogue exp + per-64col psum; reduce_rs;
// PV epilogue x 1/rs.
//
// ws: Q@0 | K@8M1 | P@16M1 ; rs over dead Q ; VT@8M1 over dead K
// d_out scratch: xb@0 | Wb@8M1 | psum@11M1 (all dead before PV writes)
// ---------------------------------------------------------------------------

typedef __attribute__((ext_vector_type(8))) short bf16x8;
typedef __attribute__((ext_vector_type(4))) float f32x4;

#define DEVI static __device__ __forceinline__

DEVI short to_bf16(float f) {
    unsigned u = __builtin_bit_cast(unsigned, f);
    u += 0x7fffu + ((u >> 16) & 1u);          // RNE (finite/normal inputs)
    return (short)(u >> 16);
}
DEVI float from_bf16(short s) {
    return __builtin_bit_cast(float, (unsigned)((unsigned short)s) << 16);
}

DEVI void gload_lds16(const short* g, short* l) {
    __builtin_amdgcn_global_load_lds(
        (const __attribute__((address_space(1))) void*)g,
        (__attribute__((address_space(3))) void*)l, 16, 0, 0);
}

#define BAR() __builtin_amdgcn_s_barrier()

// ============================ gemm256 (8-phase) ============================
// C[z][M][N] = scale*A[z].B[z]^T (+bias). bf16 K-major. K%64==0, K>=192.
// BIAS: 0=none, 1=col bias b_z[n]. EPI: 0=plain, 1=exp + psum partials.
template<int BIAS, int EPI, typename TOUT>
__global__ __launch_bounds__(512, 1)
void gemm256(const short* __restrict__ A, long lda, long bsA,
             const short* __restrict__ B, long ldb, long bsB,
             const float* __restrict__ b0, const float* __restrict__ b1,
             const float* __restrict__ b2,
             TOUT* __restrict__ c0, TOUT* __restrict__ c1, TOUT* __restrict__ c2,
             long ldc, long bsC, int K, float scale, float* __restrict__ ps)
{
    // half-tile = [128 prow][8 pchunk] 16B chunks (8192 shorts)
    __shared__ __align__(16) short Al[2][2][128 * 64];
    __shared__ __align__(16) short Bl[2][2][128 * 64];

    const int tid = threadIdx.x;
    const int z = blockIdx.z;
    const int gx = gridDim.x;
    const int nwg = gx * gridDim.y;
    const int id = blockIdx.y * gx + blockIdx.x;
    const int id2 = (id & 7) * (nwg >> 3) + (id >> 3);   // XCD swizzle (nwg%8==0)
    const long m0 = (long)(id2 / gx) * 256;
    const long n0 = (long)(id2 % gx) * 256;

    const short* Ab = A + (long)z * bsA + m0 * lda;
    const short* Bb = B + (long)z * bsB + n0 * ldb;

    const int wv = tid >> 6;
    const int wm = wv >> 2;            // 0..1 : M half
    const int wn = wv & 3;             // 0..3 : 64-col N strip
    const int lane = tid & 63;
    const int lrow = lane & 15;
    const int q = lane >> 4;           // k-quarter within a 32-k half

    const int NT = K >> 6;             // BK=64, NT>=3

    // staging: physical chunk s covers logical (row = 2*(s>>3) + (pch>>2),
    // c = pch&3) where pch = (s&7)^((s>>3)&7). Round-trip verified.
    auto stA = [&](int t, int kh) {
        const long k0 = (long)t * 64 + kh * 32;
        short* dst = &Al[t & 1][kh][0];
        #pragma unroll
        for (int i = 0; i < 2; ++i) {
            int s = i * 512 + tid;
            int prow = s >> 3;
            int pch = (s & 7) ^ (prow & 7);
            int row = prow * 2 + (pch >> 2);
            gload_lds16(Ab + (long)row * lda + k0 + (pch & 3) * 8,
                        &dst[s * 8]);
        }
    };
    auto stB = [&](int t, int kh) {
        const long k0 = (long)t * 64 + kh * 32;
        short* dst = &Bl[t & 1][kh][0];
        #pragma unroll
        for (int i = 0; i < 2; ++i) {
            int s = i * 512 + tid;
            int prow = s >> 3;
            int pch = (s & 7) ^ (prow & 7);
            int row = prow * 2 + (pch >> 2);
            gload_lds16(Bb + (long)row * ldb + k0 + (pch & 3) * 8,
                        &dst[s * 8]);
        }
    };

    bf16x8 af[4], bf[4];
    auto rdA = [&](int b, int kh, int mh) {
        #pragma unroll
        for (int m = 0; m < 4; ++m) {
            int row = wm * 128 + (mh * 4 + m) * 16 + lrow;
            int prow = row >> 1;
            int pch = (((row & 1) * 4 + q)) ^ (prow & 7);
            af[m] = *(const bf16x8*)&Al[b][kh][prow * 64 + pch * 8];
        }
    };
    auto rdB = [&](int b, int kh) {
        #pragma unroll
        for (int n = 0; n < 4; ++n) {
            int row = wn * 64 + n * 16 + lrow;
            int prow = row >> 1;
            int pch = (((row & 1) * 4 + q)) ^ (prow & 7);
            bf[n] = *(const bf16x8*)&Bl[b][kh][prow * 64 + pch * 8];
        }
    };

    f32x4 acc[8][4] = {};

    // prologue: tile0 all 4 half-tiles + tile1 k0 half-tiles (12 loads)
    stA(0, 0); stB(0, 0); stA(0, 1); stB(0, 1);
    stA(1, 0); stB(1, 0);
    asm volatile("s_waitcnt vmcnt(4)" ::: "memory");   // tile0 landed
    __builtin_amdgcn_sched_barrier(0);
    BAR();

    for (int t = 0; t < NT; ++t) {
        const int b = t & 1;
        // ---- ph1: m0-3 x kk0 (reads Ak0, Bk0; stages (t+1).Ak1 -> buf^1)
        rdA(b, 0, 0); rdB(b, 0);
        if (t + 1 < NT) stA(t + 1, 1);
        BAR();
        __builtin_amdgcn_s_setprio(1);
        #pragma unroll
        for (int m = 0; m < 4; ++m)
            #pragma unroll
            for (int n = 0; n < 4; ++n)
                acc[m][n] = __builtin_amdgcn_mfma_f32_16x16x32_bf16(
                    af[m], bf[n], acc[m][n], 0, 0, 0);
        __builtin_amdgcn_s_setprio(0);
        BAR();
        // ---- ph2: m4-7 x kk0 (B held in regs; stages (t+1).Bk1)
        rdA(b, 0, 1);
        if (t + 1 < NT) stB(t + 1, 1);
        BAR();
        __builtin_amdgcn_s_setprio(1);
        #pragma unroll
        for (int m = 0; m < 4; ++m)
            #pragma unroll
            for (int n = 0; n < 4; ++n)
                acc[4 + m][n] = __builtin_amdgcn_mfma_f32_16x16x32_bf16(
                    af[m], bf[n], acc[4 + m][n], 0, 0, 0);
        __builtin_amdgcn_s_setprio(0);
        if (t < NT - 1) asm volatile("s_waitcnt vmcnt(8)" ::: "memory");
        else            asm volatile("s_waitcnt vmcnt(0)" ::: "memory");
        __builtin_amdgcn_sched_barrier(0);
        BAR();   // t.Ak1/Bk1 landed for all waves -> ph3 may read
        // ---- ph3: m0-3 x kk1 (stages (t+2).Ak0 over dead t.Ak0)
        rdA(b, 1, 0); rdB(b, 1);
        if (t + 2 < NT) stA(t + 2, 0);
        BAR();
        __builtin_amdgcn_s_setprio(1);
        #pragma unroll
        for (int m = 0; m < 4; ++m)
            #pragma unroll
            for (int n = 0; n < 4; ++n)
                acc[m][n] = __builtin_amdgcn_mfma_f32_16x16x32_bf16(
                    af[m], bf[n], acc[m][n], 0, 0, 0);
        __builtin_amdgcn_s_setprio(0);
        BAR();
        // ---- ph4: m4-7 x kk1 (stages (t+2).Bk0 over dead t.Bk0)
        rdA(b, 1, 1);
        if (t + 2 < NT) stB(t + 2, 0);
        BAR();
        __builtin_amdgcn_s_setprio(1);
        #pragma unroll
        for (int m = 0; m < 4; ++m)
            #pragma unroll
            for (int n = 0; n < 4; ++n)
                acc[4 + m][n] = __builtin_amdgcn_mfma_f32_16x16x32_bf16(
                    af[m], bf[n], acc[4 + m][n], 0, 0, 0);
        __builtin_amdgcn_s_setprio(0);
        if (t < NT - 2) asm volatile("s_waitcnt vmcnt(8)" ::: "memory");
        else            asm volatile("s_waitcnt vmcnt(0)" ::: "memory");
        __builtin_amdgcn_sched_barrier(0);
        BAR();   // (t+1).Ak0/Bk0 landed -> next tile ph1 may read
    }

    // epilogue: C/D layout col=lane&15, row=q*4+reg (verified m89)
    const float* bias = (z == 0) ? b0 : (z == 1) ? b1 : b2;
    TOUT* Cb = (((z == 0) ? c0 : (z == 1) ? c1 : c2) + (long)z * bsC)
               + m0 * ldc + n0;
    #pragma unroll
    for (int m = 0; m < 8; ++m) {
        #pragma unroll
        for (int r = 0; r < 4; ++r) {
            int row = wm * 128 + m * 16 + q * 4 + r;
            float rsum = 0.f;
            #pragma unroll
            for (int n = 0; n < 4; ++n) {
                int col = wn * 64 + n * 16 + lrow;
                float v = acc[m][n][r] * scale;
                if constexpr (BIAS == 1) v += bias[n0 + col];
                if constexpr (EPI == 1) { v = __expf(v); rsum += v; }
                if constexpr (sizeof(TOUT) == 2)
                    Cb[(long)row * ldc + col] = to_bf16(v);
                else
                    Cb[(long)row * ldc + col] = v;
            }
            if constexpr (EPI == 1) {
                rsum += __shfl_xor(rsum, 1);
                rsum += __shfl_xor(rsum, 2);
                rsum += __shfl_xor(rsum, 4);
                rsum += __shfl_xor(rsum, 8);
                if (lrow == 0) {
                    int j = (int)(n0 >> 6) + wn;     // 0..31
                    ps[((long)z * 32 + j) * 2048 + m0 + row] = rsum;
                }
            }
        }
    }
}

// ===================== gemm97 (proven 2-barrier core) ======================
// BIAS: 0=none, 2=row bias b0[m]. EPI: 0=plain, 2=v *= 1/rs[row].
template<int BIAS, int EPI, typename TOUT>
__global__ __launch_bounds__(256, 3)
void gemm97(const short* __restrict__ A, long lda, long bsA,
            const short* __restrict__ B, long ldb, long bsB,
            const float* __restrict__ b0,
            TOUT* __restrict__ C, long ldc, long bsC, int K, float scale,
            const float* __restrict__ rs, long rsLD)
{
    __shared__ __align__(16) short As[128 * 64];
    __shared__ __align__(16) short Bs[128 * 64];

    const int tid = threadIdx.x;
    const int z = blockIdx.z;

    const int gx = gridDim.x;
    const int nwg = gx * gridDim.y;
    const int id = blockIdx.y * gx + blockIdx.x;
    const int id2 = (id & 7) * (nwg >> 3) + (id >> 3);
    const long m0 = (long)(id2 / gx) * 128;
    const long n0 = (long)(id2 % gx) * 128;

    const short* Ab = A + (long)z * bsA + m0 * lda;
    const short* Bb = B + (long)z * bsB + n0 * ldb;

    const int wv = tid >> 6;
    const int lane = tid & 63;
    const int wr = (wv >> 1) * 64;
    const int wc = (wv & 1) * 64;
    const int lrow = lane & 15;
    const int q = lane >> 4;

    const int NT = K >> 6;

    auto stage = [&](int t) {
        const long k0 = (long)t * 64;
        #pragma unroll
        for (int i = 0; i < 4; ++i) {
            int s = i * 256 + tid;
            int row = s >> 3;
            int src = (s & 7) ^ (row & 7);
            gload_lds16(Ab + (long)row * lda + k0 + src * 8, &As[s * 8]);
        }
        #pragma unroll
        for (int i = 0; i < 4; ++i) {
            int s = i * 256 + tid;
            int row = s >> 3;
            int src = (s & 7) ^ (row & 7);
            gload_lds16(Bb + (long)row * ldb + k0 + src * 8, &Bs[s * 8]);
        }
    };

    f32x4 acc[4][4] = {};

    for (int t = 0; t < NT; ++t) {
        if (t) {
            // all waves' reads of the buffer consumed (their MFMAs issued
            // => compiler lgkm waits done) before anyone restages.
            BAR();
        }
        stage(t);
        asm volatile("s_waitcnt vmcnt(0)" ::: "memory");
        __builtin_amdgcn_sched_barrier(0);
        BAR();

        bf16x8 af[4][2], bf[4][2];
        #pragma unroll
        for (int m = 0; m < 4; ++m) {
            int row = wr + m * 16 + lrow;
            #pragma unroll
            for (int kk = 0; kk < 2; ++kk) {
                int ch = (kk * 4 + q) ^ (row & 7);
                af[m][kk] = *(const bf16x8*)&As[row * 64 + ch * 8];
            }
        }
        #pragma unroll
        for (int n = 0; n < 4; ++n) {
            int row = wc + n * 16 + lrow;
            #pragma unroll
            for (int kk = 0; kk < 2; ++kk) {
                int ch = (kk * 4 + q) ^ (row & 7);
                bf[n][kk] = *(const bf16x8*)&Bs[row * 64 + ch * 8];
            }
        }

        __builtin_amdgcn_s_setprio(1);
        #pragma unroll
        for (int m = 0; m < 4; ++m)
            #pragma unroll
            for (int n = 0; n < 4; ++n)
                #pragma unroll
                for (int kk = 0; kk < 2; ++kk)
                    acc[m][n] = __builtin_amdgcn_mfma_f32_16x16x32_bf16(
                        af[m][kk], bf[n][kk], acc[m][n], 0, 0, 0);
        __builtin_amdgcn_s_setprio(0);
    }

    TOUT* Cb = C + (long)z * bsC + m0 * ldc + n0;
    #pragma unroll
    for (int m = 0; m < 4; ++m) {
        #pragma unroll
        for (int r = 0; r < 4; ++r) {
            int row = wr + m * 16 + q * 4 + r;
            float iv = 1.0f;
            if constexpr (EPI == 2)
                iv = 1.0f / rs[(long)z * rsLD + m0 + row];
            #pragma unroll
            for (int n = 0; n < 4; ++n) {
                int col = wc + n * 16 + lrow;
                float v = acc[m][n][r] * scale;
                if constexpr (BIAS == 2) v += b0[m0 + row];
                if constexpr (EPI == 2) v *= iv;
                if constexpr (sizeof(TOUT) == 2)
                    Cb[(long)row * ldc + col] = to_bf16(v);
                else
                    Cb[(long)row * ldc + col] = v;
            }
        }
    }
}

// merged cvt: grid (512, 11). y<8: x chunks (fp32->bf16). y=8,9,10: Wq,Wk,Wv.
__global__ __launch_bounds__(256)
void cvt_all(const float* __restrict__ x,
             const float* __restrict__ wq, const float* __restrict__ wk,
             const float* __restrict__ wv, short* __restrict__ dst)
{
    const int y = blockIdx.y;
    const float* src;
    long dstOff8;
    long i;
    if (y < 8) {
        src = x;
        i = ((long)y * 512 + blockIdx.x) * 256 + threadIdx.x;
        dstOff8 = 0;
    } else {
        src = (y == 8) ? wq : (y == 9) ? wk : wv;
        i = (long)blockIdx.x * 256 + threadIdx.x;
        dstOff8 = (8l * 1024 * 1024 + (long)(y - 8) * 1024 * 1024) / 8;
    }
    float4 a = ((const float4*)src)[2 * i];
    float4 b = ((const float4*)src)[2 * i + 1];
    bf16x8 o = { to_bf16(a.x), to_bf16(a.y), to_bf16(a.z), to_bf16(a.w),
                 to_bf16(b.x), to_bf16(b.y), to_bf16(b.z), to_bf16(b.w) };
    *(bf16x8*)&dst[(dstOff8 + i) * 8] = o;
}

// rs[row] = sum_{j<32} ps[(z*32+j)*2048 + r]
__global__ __launch_bounds__(256)
void reduce_rs(const float* __restrict__ ps, float* __restrict__ rs)
{
    int row = blockIdx.x * 256 + threadIdx.x;   // 0..8191
    int z = row >> 11, r = row & 2047;
    const float* p = ps + (long)z * 32 * 2048 + r;
    float s = 0.f;
    #pragma unroll
    for (int j = 0; j < 32; ++j) s += p[j * 2048];
    rs[row] = s;
}

extern "C" void kernel_launch(void* const* d_in, const int* in_sizes, int n_in,
                              void* d_out, int out_size, void* d_ws, size_t ws_size,
                              hipStream_t stream)
{
    (void)in_sizes; (void)n_in; (void)out_size; (void)ws_size;

    const float* x  = (const float*)d_in[0];
    const float* Wq = (const float*)d_in[1];
    const float* bq = (const float*)d_in[2];
    const float* Wk = (const float*)d_in[3];
    const float* bk = (const float*)d_in[4];
    const float* Wv = (const float*)d_in[5];
    const float* bv = (const float*)d_in[6];
    float* out = (float*)d_out;

    const int S = 2048, E = 1024;
    const long M1 = 1024l * 1024;

    // ws regions (shorts)
    short* w  = (short*)d_ws;
    short* Q  = w;                  // [4][2048][1024]  (16MB)
    short* Kb = w + 8 * M1;         // [4][2048][1024]  (16MB)
    short* P  = w + 16 * M1;        // [4][2048][2048]  (32MB) exp(scores)
    float* rs = (float*)w;          // [4][2048] fp32 over dead Q
    short* VT = w + 8 * M1;         // [4][1024][2048] over dead K (post-scores)

    // d_out scratch (xb/Wb last read by VT-GEMM; psum by reduce_rs)
    short* dows = (short*)d_out;
    short* xb = dows;               // [8192][1024] bf16 (16MB)
    short* Wb = dows + 8 * M1;      // Wq,Wk,Wv bf16 (3 x 2MB)
    float* psum = (float*)(dows + 11 * M1);   // [4][32][2048] fp32 (1MB)

    dim3 blk(256), blk5(512);

    // 1. convert inputs to bf16
    cvt_all<<<dim3(512, 11), blk, 0, stream>>>(x, Wq, Wk, Wv, xb);

    // 2. Q,K projections (M=8192,N=1024,K=1024): 8-phase, grid 4x32x2 = 256
    gemm256<1, 0, short><<<dim3(4, 32, 2), blk5, 0, stream>>>(
        xb, E, 0, Wb, E, M1, bq, bk, nullptr, Q, Kb, nullptr, E, 0, E, 1.0f,
        nullptr);

    // 3. scores: P[z] = exp(Q K^T / 32) + psum (M=N=2048,K=1024): 8x8x4 = 256
    gemm256<0, 1, short><<<dim3(8, 8, 4), blk5, 0, stream>>>(
        Q, E, 2 * M1, Kb, E, 2 * M1, nullptr, nullptr, nullptr,
        P, P, P, S, 4 * M1, E, 0.03125f, psum);

    // 4. VT[z] = Wv xb[z]^T + bv (row bias) (M=1024,N=2048,K=1024): 16x8x4
    gemm97<2, 0, short><<<dim3(16, 8, 4), blk, 0, stream>>>(
        Wb + 2 * M1, E, 0, xb, E, 2 * M1, bv, VT, S, 2 * M1, E, 1.0f,
        nullptr, 0);

    // 5. rs[row] = sum of 32 partials (over dead Q)
    reduce_rs<<<dim3(32), blk, 0, stream>>>(psum, rs);

    // 6. out[z] = (P[z] VT[z]^T) / rs (M=2048,N=1024,K=2048): 8x16x4, fp32
    gemm97<0, 2, float><<<dim3(8, 16, 4), blk, 0, stream>>>(
        P, S, 4 * M1, VT, S, 2 * M1, nullptr, out, E, 2 * M1, S, 1.0f,
        rs, S);
}